// Round 2
// baseline (264.906 us; speedup 1.0000x reference)
//
#include <hip/hip_runtime.h>
#include <cstdint>
#include <cstddef>

// Problem constants (SparseLinear: B=4096, IN=4096, OUT=4096, NNZ=1677722)
#define IN_F  4096
#define OUT_F 4096
#define BATCH 4096

typedef __bf16 bf16_t;
typedef __bf16 bf16x8 __attribute__((ext_vector_type(8)));
typedef float  f32x4  __attribute__((ext_vector_type(4)));

// ---------------------------------------------------------------------------
// f32 -> bf16 round-to-nearest-even (bit trick, deterministic)
// ---------------------------------------------------------------------------
__device__ __forceinline__ unsigned short f32_to_bf16_rne(float f) {
  union { float f; unsigned int u; } v;
  v.f = f;
  unsigned int u = v.u;
  return (unsigned short)((u + 0x7FFFu + ((u >> 16) & 1u)) >> 16);
}

// ---------------------------------------------------------------------------
// Scatter-add COO weights into dense f32 W (OUT_F x IN_F), duplicates summed.
// active_mask is a bool input; harness materializes integer-family dtypes as
// int32 (R1 evidence: uint8 read kept 25% of weights -> absmax 1.93 == max of
// N(0, 0.75*sigma_w^2*fanin) over 16.7M samples).
// ---------------------------------------------------------------------------
__global__ __launch_bounds__(256) void scatter_kernel(
    const float* __restrict__ w, const int* __restrict__ rows,
    const int* __restrict__ cols, const int* __restrict__ mask,
    float* __restrict__ W, int nnz) {
  int i = blockIdx.x * 256 + threadIdx.x;
  if (i < nnz) {
    if (mask[i] != 0) {
      atomicAdd(&W[(size_t)rows[i] * IN_F + cols[i]], w[i]);
    }
  }
}

// ---------------------------------------------------------------------------
// Vectorized f32 -> bf16 conversion: 8 elems/thread (2x float4 in, 1x uint4 out)
// ---------------------------------------------------------------------------
__global__ __launch_bounds__(256) void cvt_f32_bf16(
    const float4* __restrict__ in, uint4* __restrict__ out, int n8) {
  int i = blockIdx.x * 256 + threadIdx.x;
  if (i >= n8) return;
  float4 a = in[2 * i];
  float4 b = in[2 * i + 1];
  uint4 o;
  o.x = (unsigned)f32_to_bf16_rne(a.x) | ((unsigned)f32_to_bf16_rne(a.y) << 16);
  o.y = (unsigned)f32_to_bf16_rne(a.z) | ((unsigned)f32_to_bf16_rne(a.w) << 16);
  o.z = (unsigned)f32_to_bf16_rne(b.x) | ((unsigned)f32_to_bf16_rne(b.y) << 16);
  o.w = (unsigned)f32_to_bf16_rne(b.z) | ((unsigned)f32_to_bf16_rne(b.w) << 16);
  out[i] = o;
}

// ---------------------------------------------------------------------------
// bf16 GEMM, C = A @ B^T  (A: MxK row-major, Bm: NxK row-major, C: MxN f32)
// m97 structure: 128x128 tile, BK=32, 4 waves (2x2), each wave 64x64 = 4x4
// frags of mfma_f32_16x16x32_bf16. global_load_lds width=16 staging,
// 2-barrier K-loop (compiler drains vmcnt at the barrier).
// ---------------------------------------------------------------------------
#define BM 128
#define BK 32

__global__ __launch_bounds__(256, 2) void gemm_bt(
    const bf16_t* __restrict__ A, const bf16_t* __restrict__ Bm,
    float* __restrict__ C, int M, int N, int K) {
  __shared__ __align__(16) bf16_t As[BM * BK];  // [row][k], 64B rows, linear
  __shared__ __align__(16) bf16_t Bs[BM * BK];

  const int tid  = threadIdx.x;
  const int lane = tid & 63;
  const int wave = tid >> 6;
  const int wr   = wave >> 1;  // wave row (0..1)
  const int wc   = wave & 1;   // wave col (0..1)
  const int bm   = blockIdx.x;
  const int bn   = blockIdx.y;

  // Staging: each thread owns 8 bf16 (16B). Two chunks per tile (128*32/2048).
  const int e0 = tid * 8;        // chunk-0 element offset in LDS
  const int r0 = e0 >> 5;        // row 0..63 (chunk 1 adds +64)
  const int kk = e0 & 31;        // k within tile

  const size_t aRow = (size_t)bm * BM + r0;
  const size_t bRow = (size_t)bn * BM + r0;
  const bf16_t* gA0 = A  + aRow * K + kk;
  const bf16_t* gA1 = A  + (aRow + 64) * K + kk;
  const bf16_t* gB0 = Bm + bRow * K + kk;
  const bf16_t* gB1 = Bm + (bRow + 64) * K + kk;

  bf16_t* lA0 = &As[e0];
  bf16_t* lA1 = &As[e0 + 2048];
  bf16_t* lB0 = &Bs[e0];
  bf16_t* lB1 = &Bs[e0 + 2048];

  f32x4 acc[4][4] = {};

  const int frow = lane & 15;         // row within 16x16 A-frag / col of B-frag
  const int koff = (lane >> 4) * 8;   // k offset within BK

  for (int k0 = 0; k0 < K; k0 += BK) {
    // --- async stage global -> LDS (16B per lane per issue) ---
    __builtin_amdgcn_global_load_lds(
        (const __attribute__((address_space(1))) void*)(gA0 + k0),
        (__attribute__((address_space(3))) void*)lA0, 16, 0, 0);
    __builtin_amdgcn_global_load_lds(
        (const __attribute__((address_space(1))) void*)(gA1 + k0),
        (__attribute__((address_space(3))) void*)lA1, 16, 0, 0);
    __builtin_amdgcn_global_load_lds(
        (const __attribute__((address_space(1))) void*)(gB0 + k0),
        (__attribute__((address_space(3))) void*)lB0, 16, 0, 0);
    __builtin_amdgcn_global_load_lds(
        (const __attribute__((address_space(1))) void*)(gB1 + k0),
        (__attribute__((address_space(3))) void*)lB1, 16, 0, 0);

    __syncthreads();  // drains vmcnt -> staged data visible

    bf16x8 a[4], b[4];
#pragma unroll
    for (int mi = 0; mi < 4; ++mi)
      a[mi] = *(const bf16x8*)&As[(wr * 64 + mi * 16 + frow) * BK + koff];
#pragma unroll
    for (int ni = 0; ni < 4; ++ni)
      b[ni] = *(const bf16x8*)&Bs[(wc * 64 + ni * 16 + frow) * BK + koff];

#pragma unroll
    for (int mi = 0; mi < 4; ++mi)
#pragma unroll
      for (int ni = 0; ni < 4; ++ni)
        acc[mi][ni] = __builtin_amdgcn_mfma_f32_16x16x32_bf16(
            a[mi], b[ni], acc[mi][ni], 0, 0, 0);

    __syncthreads();  // all waves done reading before next-tile overwrite
  }

  // Epilogue: C/D layout col = lane&15, row = (lane>>4)*4 + j  [m89-verified]
  const int crow0 = bm * BM + wr * 64 + (lane >> 4) * 4;
  const int ccol0 = bn * BM + wc * 64 + (lane & 15);
#pragma unroll
  for (int mi = 0; mi < 4; ++mi) {
#pragma unroll
    for (int ni = 0; ni < 4; ++ni) {
      const int row = crow0 + mi * 16;
      const int col = ccol0 + ni * 16;
#pragma unroll
      for (int j = 0; j < 4; ++j)
        C[(size_t)(row + j) * N + col] = acc[mi][ni][j];
    }
  }
}

// ---------------------------------------------------------------------------
extern "C" void kernel_launch(void* const* d_in, const int* in_sizes, int n_in,
                              void* d_out, int out_size, void* d_ws, size_t ws_size,
                              hipStream_t stream) {
  const float* x     = (const float*)d_in[0];
  const float* wvals = (const float*)d_in[1];
  const int*   idx   = (const int*)d_in[2];   // (2, nnz): rows then cols
  const int*   mk    = (const int*)d_in[3];   // bool -> int32 on device (R1)
  const int    nnz   = in_sizes[1];

  // Layout: d_out doubles as the f32 W accumulator (64MB) before GEMM
  // overwrites it with y. ws: [0,32MB) = W bf16, [32MB,64MB) = x bf16.
  float*  Wf32 = (float*)d_out;
  bf16_t* Wbf  = (bf16_t*)d_ws;
  bf16_t* xbf  = (bf16_t*)((char*)d_ws + (size_t)OUT_F * IN_F * sizeof(bf16_t));

  const size_t needed = (size_t)OUT_F * IN_F * 2 + (size_t)BATCH * IN_F * 2;
  if (ws_size < needed) return;  // loud failure: output stays poisoned

  // 1. zero the f32 W accumulator (graph-capturable memset)
  hipMemsetAsync(d_out, 0, (size_t)OUT_F * IN_F * sizeof(float), stream);

  // 2. scatter-add active weights (duplicates summed = coalesce semantics)
  scatter_kernel<<<(nnz + 255) / 256, 256, 0, stream>>>(
      wvals, idx, idx + nnz, mk, Wf32, nnz);

  // 3. W f32 -> bf16
  const int w8 = (OUT_F * IN_F) / 8;
  cvt_f32_bf16<<<(w8 + 255) / 256, 256, 0, stream>>>(
      (const float4*)Wf32, (uint4*)Wbf, w8);

  // 4. x f32 -> bf16
  const int x8 = (BATCH * IN_F) / 8;
  cvt_f32_bf16<<<(x8 + 255) / 256, 256, 0, stream>>>(
      (const float4*)x, (uint4*)xbf, x8);

  // 5. y = x @ W^T  (bf16 MFMA, f32 accumulate) -> d_out
  gemm_bt<<<dim3(BATCH / BM, OUT_F / BM), 256, 0, stream>>>(
      xbf, Wbf, (float*)d_out, BATCH, OUT_F, IN_F);
}

// Round 3
// 238.338 us; speedup vs baseline: 1.1115x; 1.1115x over previous
//
#include <hip/hip_runtime.h>
#include <cstdint>
#include <cstddef>

// Problem constants (SparseLinear: B=4096, IN=4096, OUT=4096, NNZ=1677722)
#define IN_F  4096
#define OUT_F 4096
#define BATCH 4096

typedef __bf16 bf16_t;
typedef __bf16 bf16x8 __attribute__((ext_vector_type(8)));
typedef float  f32x4  __attribute__((ext_vector_type(4)));

// ---------------------------------------------------------------------------
// f32 -> bf16 round-to-nearest-even (bit trick, deterministic)
// ---------------------------------------------------------------------------
__device__ __forceinline__ unsigned short f32_to_bf16_rne(float f) {
  union { float f; unsigned int u; } v;
  v.f = f;
  unsigned int u = v.u;
  return (unsigned short)((u + 0x7FFFu + ((u >> 16) & 1u)) >> 16);
}

// ---------------------------------------------------------------------------
// Scatter-add COO weights into dense f32 W. mask is int32 on device (R1).
// ---------------------------------------------------------------------------
__global__ __launch_bounds__(256) void scatter_kernel(
    const float* __restrict__ w, const int* __restrict__ rows,
    const int* __restrict__ cols, const int* __restrict__ mask,
    float* __restrict__ W, int nnz) {
  int i = blockIdx.x * 256 + threadIdx.x;
  if (i < nnz) {
    if (mask[i] != 0) {
      atomicAdd(&W[(size_t)rows[i] * IN_F + cols[i]], w[i]);
    }
  }
}

// ---------------------------------------------------------------------------
// Vectorized f32 -> bf16 conversion: 8 elems/thread
// ---------------------------------------------------------------------------
__global__ __launch_bounds__(256) void cvt_f32_bf16(
    const float4* __restrict__ in, uint4* __restrict__ out, int n8) {
  int i = blockIdx.x * 256 + threadIdx.x;
  if (i >= n8) return;
  float4 a = in[2 * i];
  float4 b = in[2 * i + 1];
  uint4 o;
  o.x = (unsigned)f32_to_bf16_rne(a.x) | ((unsigned)f32_to_bf16_rne(a.y) << 16);
  o.y = (unsigned)f32_to_bf16_rne(a.z) | ((unsigned)f32_to_bf16_rne(a.w) << 16);
  o.z = (unsigned)f32_to_bf16_rne(b.x) | ((unsigned)f32_to_bf16_rne(b.y) << 16);
  o.w = (unsigned)f32_to_bf16_rne(b.z) | ((unsigned)f32_to_bf16_rne(b.w) << 16);
  out[i] = o;
}

// ---------------------------------------------------------------------------
// 256x256 8-phase bf16 GEMM, C = A @ Bm^T (both row-major [4096][4096]).
// T1 XCD swizzle + T2 LDS XOR-swizzle + T3/T4 8-phase counted vmcnt + T5
// setprio. LDS layout per tile: [ks(2)][256 rows][32 cols] bf16 -> each
// ks-half is a contiguous 16KB region (gload_lds-stageable), row stride 64B.
// Swizzle (involution on byte addr within half): phys = logical ^ ((row&3)<<4).
// Write side pre-permutes the GLOBAL source (rule #21): thread tid loads
// global chunk ((tid&3) ^ ((tid>>2)&3)) of row tid>>2 (+128 for 2nd issue).
// Pipeline ledger (t = 2i):  stage slots per iteration
//   ph1:A(t+1)ks1->buf1A  ph2:B(t+1)ks1->buf1B  ph3:A(t+2)ks0->buf0A
//   ph4:B(t+2)ks0->buf0B  ph5:A(t+2)ks1->buf0A  ph6:B(t+2)ks1->buf0B
//   ph7:A(t+3)ks0->buf1A  ph8:B(t+3)ks0->buf1B
// Every written region is dead (last read >=1 barrier earlier); vmcnt(4) at
// ph4 drains tile t+1 (needed ph5-8), vmcnt(4) at ph8 drains tile t+2
// (needed next-iter ph1-4). 12 loads in flight steady state, never 0.
// ---------------------------------------------------------------------------
#define A0_B 0
#define B0_B 32768
#define A1_B 65536
#define B1_B 98304
#define HALF 16384

#define STAGE(Xg, kpos, ldsbase) do {                                          \
  __builtin_amdgcn_global_load_lds(                                            \
    (const __attribute__((address_space(1))) void*)((Xg) + (size_t)srow * 4096 + (kpos) + schunk), \
    (__attribute__((address_space(3))) void*)(lds + (ldsbase) + tid * 16), 16, 0, 0); \
  __builtin_amdgcn_global_load_lds(                                            \
    (const __attribute__((address_space(1))) void*)((Xg) + (size_t)(srow + 128) * 4096 + (kpos) + schunk), \
    (__attribute__((address_space(3))) void*)(lds + (ldsbase) + 8192 + tid * 16), 16, 0, 0); \
} while (0)

#define LDA4(base, mh) do {                                                    \
  a0 = *(const bf16x8*)(lds + (base) + offA[mh][0]);                           \
  a1 = *(const bf16x8*)(lds + (base) + offA[mh][1]);                           \
  a2 = *(const bf16x8*)(lds + (base) + offA[mh][2]);                           \
  a3 = *(const bf16x8*)(lds + (base) + offA[mh][3]);                           \
} while (0)

#define LDB4(base) do {                                                        \
  b0 = *(const bf16x8*)(lds + (base) + offB[0]);                               \
  b1 = *(const bf16x8*)(lds + (base) + offB[1]);                               \
  b2 = *(const bf16x8*)(lds + (base) + offB[2]);                               \
  b3 = *(const bf16x8*)(lds + (base) + offB[3]);                               \
} while (0)

#define MFMA16(mh) do {                                                        \
  acc[(mh)*4+0][0] = __builtin_amdgcn_mfma_f32_16x16x32_bf16(a0, b0, acc[(mh)*4+0][0], 0, 0, 0); \
  acc[(mh)*4+0][1] = __builtin_amdgcn_mfma_f32_16x16x32_bf16(a0, b1, acc[(mh)*4+0][1], 0, 0, 0); \
  acc[(mh)*4+0][2] = __builtin_amdgcn_mfma_f32_16x16x32_bf16(a0, b2, acc[(mh)*4+0][2], 0, 0, 0); \
  acc[(mh)*4+0][3] = __builtin_amdgcn_mfma_f32_16x16x32_bf16(a0, b3, acc[(mh)*4+0][3], 0, 0, 0); \
  acc[(mh)*4+1][0] = __builtin_amdgcn_mfma_f32_16x16x32_bf16(a1, b0, acc[(mh)*4+1][0], 0, 0, 0); \
  acc[(mh)*4+1][1] = __builtin_amdgcn_mfma_f32_16x16x32_bf16(a1, b1, acc[(mh)*4+1][1], 0, 0, 0); \
  acc[(mh)*4+1][2] = __builtin_amdgcn_mfma_f32_16x16x32_bf16(a1, b2, acc[(mh)*4+1][2], 0, 0, 0); \
  acc[(mh)*4+1][3] = __builtin_amdgcn_mfma_f32_16x16x32_bf16(a1, b3, acc[(mh)*4+1][3], 0, 0, 0); \
  acc[(mh)*4+2][0] = __builtin_amdgcn_mfma_f32_16x16x32_bf16(a2, b0, acc[(mh)*4+2][0], 0, 0, 0); \
  acc[(mh)*4+2][1] = __builtin_amdgcn_mfma_f32_16x16x32_bf16(a2, b1, acc[(mh)*4+2][1], 0, 0, 0); \
  acc[(mh)*4+2][2] = __builtin_amdgcn_mfma_f32_16x16x32_bf16(a2, b2, acc[(mh)*4+2][2], 0, 0, 0); \
  acc[(mh)*4+2][3] = __builtin_amdgcn_mfma_f32_16x16x32_bf16(a2, b3, acc[(mh)*4+2][3], 0, 0, 0); \
  acc[(mh)*4+3][0] = __builtin_amdgcn_mfma_f32_16x16x32_bf16(a3, b0, acc[(mh)*4+3][0], 0, 0, 0); \
  acc[(mh)*4+3][1] = __builtin_amdgcn_mfma_f32_16x16x32_bf16(a3, b1, acc[(mh)*4+3][1], 0, 0, 0); \
  acc[(mh)*4+3][2] = __builtin_amdgcn_mfma_f32_16x16x32_bf16(a3, b2, acc[(mh)*4+3][2], 0, 0, 0); \
  acc[(mh)*4+3][3] = __builtin_amdgcn_mfma_f32_16x16x32_bf16(a3, b3, acc[(mh)*4+3][3], 0, 0, 0); \
} while (0)

#define BAR()   __builtin_amdgcn_s_barrier()
#define LGKM0() do { asm volatile("s_waitcnt lgkmcnt(0)" ::: "memory");        \
                     __builtin_amdgcn_sched_barrier(0); } while (0)
#define VM(n)   asm volatile("s_waitcnt vmcnt(" #n ")" ::: "memory")
#define PRIO1() __builtin_amdgcn_s_setprio(1)
#define PRIO0() __builtin_amdgcn_s_setprio(0)

__global__ __launch_bounds__(512, 2) void gemm_bt_8ph(
    const bf16_t* __restrict__ A, const bf16_t* __restrict__ Bm,
    float* __restrict__ C) {
  __shared__ __align__(16) char lds[131072];

  const int tid  = threadIdx.x;
  const int lane = tid & 63;
  const int wave = tid >> 6;
  const int wm   = wave >> 2;  // 0..1  (M half of block)
  const int wn   = wave & 3;   // 0..3  (N quarter of block)

  // T1: XCD-aware swizzle; 256 blocks % 8 == 0 -> bijective
  const int sbid = (blockIdx.x & 7) * 32 + (blockIdx.x >> 3);
  const int bm   = sbid >> 4;
  const int bn   = sbid & 15;

  const int frow = lane & 15;
  const int c16  = (lane >> 4) * 16;  // 16B chunk within 64B row

  // ds_read byte offsets within a ks-half [256][32] region (T2-swizzled)
  int offA[2][4], offB[4];
#pragma unroll
  for (int mh = 0; mh < 2; ++mh)
#pragma unroll
    for (int mi = 0; mi < 4; ++mi) {
      int r = wm * 128 + mh * 64 + mi * 16 + frow;
      offA[mh][mi] = r * 64 + (c16 ^ ((r & 3) << 4));
    }
#pragma unroll
  for (int ni = 0; ni < 4; ++ni) {
    int r = wn * 64 + ni * 16 + frow;
    offB[ni] = r * 64 + (c16 ^ ((r & 3) << 4));
  }

  // staging invariants (write-side inverse of the read swizzle; verified:
  // phys(tid,j) == read_addr(row=tid>>2+128j, chunk=(tid&3)^((tid>>2)&3)))
  const int srow   = tid >> 2;
  const int schunk = ((tid & 3) ^ (srow & 3)) * 8;
  const bf16_t* Ag = A  + (size_t)bm * 256 * 4096;
  const bf16_t* Bg = Bm + (size_t)bn * 256 * 4096;

  f32x4 acc[8][4] = {};
  bf16x8 a0, a1, a2, a3, b0, b1, b2, b3;

  // ---- prologue: tile0 (full) + tile1 ks0; drain tile0, keep tile1 in flight
  STAGE(Ag, 0,  A0_B);
  STAGE(Bg, 0,  B0_B);
  STAGE(Ag, 32, A0_B + HALF);
  STAGE(Bg, 32, B0_B + HALF);
  STAGE(Ag, 64, A1_B);
  STAGE(Bg, 64, B1_B);
  VM(4);
  BAR();

  int kb = 0;
#pragma unroll 1
  for (int i = 0; i < 31; ++i, kb += 128) {
    // ph1: tile t ks0 mh0
    LDA4(A0_B, 0); LDB4(B0_B);
    STAGE(Ag, kb + 96, A1_B + HALF);
    BAR(); LGKM0(); PRIO1(); MFMA16(0); PRIO0(); BAR();
    // ph2: tile t ks0 mh1
    LDA4(A0_B, 1);
    STAGE(Bg, kb + 96, B1_B + HALF);
    BAR(); LGKM0(); PRIO1(); MFMA16(1); PRIO0(); BAR();
    // ph3: tile t ks1 mh0
    LDA4(A0_B + HALF, 0); LDB4(B0_B + HALF);
    STAGE(Ag, kb + 128, A0_B);
    BAR(); LGKM0(); PRIO1(); MFMA16(0); PRIO0(); BAR();
    // ph4: tile t ks1 mh1   [counted drain: tile t+1 fully landed]
    LDA4(A0_B + HALF, 1);
    STAGE(Bg, kb + 128, B0_B);
    BAR(); LGKM0(); PRIO1(); MFMA16(1); PRIO0(); VM(4); BAR();
    // ph5: tile t+1 ks0 mh0
    LDA4(A1_B, 0); LDB4(B1_B);
    STAGE(Ag, kb + 160, A0_B + HALF);
    BAR(); LGKM0(); PRIO1(); MFMA16(0); PRIO0(); BAR();
    // ph6: tile t+1 ks0 mh1
    LDA4(A1_B, 1);
    STAGE(Bg, kb + 160, B0_B + HALF);
    BAR(); LGKM0(); PRIO1(); MFMA16(1); PRIO0(); BAR();
    // ph7: tile t+1 ks1 mh0
    LDA4(A1_B + HALF, 0); LDB4(B1_B + HALF);
    STAGE(Ag, kb + 192, A1_B);
    BAR(); LGKM0(); PRIO1(); MFMA16(0); PRIO0(); BAR();
    // ph8: tile t+1 ks1 mh1  [counted drain: tile t+2 fully landed]
    LDA4(A1_B + HALF, 1);
    STAGE(Bg, kb + 192, B1_B);
    BAR(); LGKM0(); PRIO1(); MFMA16(1); PRIO0(); VM(4); BAR();
  }

  // ---- epilogue: tiles 62 (buf0) and 63 (buf1); kb == 3968
  LDA4(A0_B, 0); LDB4(B0_B);
  STAGE(Ag, kb + 96, A1_B + HALF);          // A(63)ks1
  BAR(); LGKM0(); PRIO1(); MFMA16(0); PRIO0(); BAR();
  LDA4(A0_B, 1);
  STAGE(Bg, kb + 96, B1_B + HALF);          // B(63)ks1
  BAR(); LGKM0(); PRIO1(); MFMA16(1); PRIO0(); BAR();
  LDA4(A0_B + HALF, 0); LDB4(B0_B + HALF);
  BAR(); LGKM0(); PRIO1(); MFMA16(0); PRIO0(); BAR();
  LDA4(A0_B + HALF, 1);
  BAR(); LGKM0(); PRIO1(); MFMA16(1); PRIO0(); VM(0); BAR();
  LDA4(A1_B, 0); LDB4(B1_B);
  BAR(); LGKM0(); PRIO1(); MFMA16(0); PRIO0(); BAR();
  LDA4(A1_B, 1);
  BAR(); LGKM0(); PRIO1(); MFMA16(1); PRIO0(); BAR();
  LDA4(A1_B + HALF, 0); LDB4(B1_B + HALF);
  BAR(); LGKM0(); PRIO1(); MFMA16(0); PRIO0(); BAR();
  LDA4(A1_B + HALF, 1);
  LGKM0(); PRIO1(); MFMA16(1); PRIO0();

  // ---- C write (D layout: col = lane&15, row = (lane>>4)*4 + jj)
#pragma unroll
  for (int mh = 0; mh < 2; ++mh)
#pragma unroll
    for (int mi = 0; mi < 4; ++mi)
#pragma unroll
      for (int ni = 0; ni < 4; ++ni) {
        const int row = bm * 256 + wm * 128 + mh * 64 + mi * 16 + (lane >> 4) * 4;
        const int col = bn * 256 + wn * 64 + ni * 16 + frow;
#pragma unroll
        for (int jj = 0; jj < 4; ++jj)
          C[(size_t)(row + jj) * 4096 + col] = acc[mh * 4 + mi][ni][jj];
      }
}

// ---------------------------------------------------------------------------
extern "C" void kernel_launch(void* const* d_in, const int* in_sizes, int n_in,
                              void* d_out, int out_size, void* d_ws, size_t ws_size,
                              hipStream_t stream) {
  const float* x     = (const float*)d_in[0];
  const float* wvals = (const float*)d_in[1];
  const int*   idx   = (const int*)d_in[2];   // (2, nnz): rows then cols
  const int*   mk    = (const int*)d_in[3];   // bool -> int32 on device (R1)
  const int    nnz   = in_sizes[1];

  // d_out doubles as the f32 W accumulator before GEMM overwrites it with y.
  float*  Wf32 = (float*)d_out;
  bf16_t* Wbf  = (bf16_t*)d_ws;
  bf16_t* xbf  = (bf16_t*)((char*)d_ws + (size_t)OUT_F * IN_F * sizeof(bf16_t));

  const size_t needed = (size_t)OUT_F * IN_F * 2 + (size_t)BATCH * IN_F * 2;
  if (ws_size < needed) return;

  hipMemsetAsync(d_out, 0, (size_t)OUT_F * IN_F * sizeof(float), stream);

  scatter_kernel<<<(nnz + 255) / 256, 256, 0, stream>>>(
      wvals, idx, idx + nnz, mk, Wf32, nnz);

  const int w8 = (OUT_F * IN_F) / 8;
  cvt_f32_bf16<<<(w8 + 255) / 256, 256, 0, stream>>>(
      (const float4*)Wf32, (uint4*)Wbf, w8);

  const int x8 = (BATCH * IN_F) / 8;
  cvt_f32_bf16<<<(x8 + 255) / 256, 256, 0, stream>>>(
      (const float4*)x, (uint4*)xbf, x8);

  gemm_bt_8ph<<<256, 512, 0, stream>>>(xbf, Wbf, (float*)d_out);
}

// Round 4
// 228.727 us; speedup vs baseline: 1.1582x; 1.0420x over previous
//
#include <hip/hip_runtime.h>
#include <cstdint>
#include <cstddef>

// Problem constants (SparseLinear: B=4096, IN=4096, OUT=4096, NNZ=1677722)
#define IN_F  4096
#define OUT_F 4096
#define BATCH 4096

typedef __bf16 bf16_t;
typedef __bf16 bf16x8 __attribute__((ext_vector_type(8)));
typedef float  f32x4  __attribute__((ext_vector_type(4)));

// ---------------------------------------------------------------------------
// f32 -> bf16 round-to-nearest-even (bit trick, deterministic)
// ---------------------------------------------------------------------------
__device__ __forceinline__ unsigned short f32_to_bf16_rne(float f) {
  union { float f; unsigned int u; } v;
  v.f = f;
  unsigned int u = v.u;
  return (unsigned short)((u + 0x7FFFu + ((u >> 16) & 1u)) >> 16);
}

// ---------------------------------------------------------------------------
// Scatter-add COO weights into dense f32 W. mask is int32 on device (R1).
// ---------------------------------------------------------------------------
__global__ __launch_bounds__(256) void scatter_kernel(
    const float* __restrict__ w, const int* __restrict__ rows,
    const int* __restrict__ cols, const int* __restrict__ mask,
    float* __restrict__ W, int nnz) {
  int i = blockIdx.x * 256 + threadIdx.x;
  if (i < nnz) {
    if (mask[i] != 0) {
      atomicAdd(&W[(size_t)rows[i] * IN_F + cols[i]], w[i]);
    }
  }
}

// ---------------------------------------------------------------------------
// Vectorized f32 -> bf16 conversion: 8 elems/thread
// ---------------------------------------------------------------------------
__global__ __launch_bounds__(256) void cvt_f32_bf16(
    const float4* __restrict__ in, uint4* __restrict__ out, int n8) {
  int i = blockIdx.x * 256 + threadIdx.x;
  if (i >= n8) return;
  float4 a = in[2 * i];
  float4 b = in[2 * i + 1];
  uint4 o;
  o.x = (unsigned)f32_to_bf16_rne(a.x) | ((unsigned)f32_to_bf16_rne(a.y) << 16);
  o.y = (unsigned)f32_to_bf16_rne(a.z) | ((unsigned)f32_to_bf16_rne(a.w) << 16);
  o.z = (unsigned)f32_to_bf16_rne(b.x) | ((unsigned)f32_to_bf16_rne(b.y) << 16);
  o.w = (unsigned)f32_to_bf16_rne(b.z) | ((unsigned)f32_to_bf16_rne(b.w) << 16);
  out[i] = o;
}

// ---------------------------------------------------------------------------
// 256x256 8-phase bf16 GEMM, C = A @ Bm^T (both row-major [4096][4096]).
// T1 XCD swizzle + T2 LDS XOR-swizzle + T3/T4 8-phase counted vmcnt + T5
// setprio. LDS layout per tile: [ks(2)][256 rows][32 cols] bf16 -> each
// ks-half is a contiguous 16KB region, 64B rows = 4 x 16B slots.
// R3 post-mortem: slot = c ^ (row&3) was 4-way conflicted because bit0 of
// (row&3) == row&1 == the bank-half bit (bank = (row&1)*16 + slot*4).
// Fix: slot = c ^ ((row>>1)&3) -> bank-group (row&1, (row>>1)&3) covers all
// 8 groups over 8 consecutive rows; quarter-wave = 2-way = free (m136).
// Write side (rule #21, both-sides-or-neither): thread tid stages LDS
// linearly at tid*16 (row tid>>2, phys slot tid&3) from GLOBAL chunk
// (tid&3) ^ ((row>>1)&3) -> phys slot p holds logical chunk p ^ s(row). ✓
// Pipeline ledger unchanged from R3 (vmcnt(4) at ph4/ph8, 12 loads in
// flight steady-state, regions dead >=1 barrier before overwrite).
// ---------------------------------------------------------------------------
#define A0_B 0
#define B0_B 32768
#define A1_B 65536
#define B1_B 98304
#define HALF 16384

#define STAGE(Xg, kpos, ldsbase) do {                                          \
  __builtin_amdgcn_global_load_lds(                                            \
    (const __attribute__((address_space(1))) void*)((Xg) + (size_t)srow * 4096 + (kpos) + schunk), \
    (__attribute__((address_space(3))) void*)(lds + (ldsbase) + tid * 16), 16, 0, 0); \
  __builtin_amdgcn_global_load_lds(                                            \
    (const __attribute__((address_space(1))) void*)((Xg) + (size_t)(srow + 128) * 4096 + (kpos) + schunk2), \
    (__attribute__((address_space(3))) void*)(lds + (ldsbase) + 8192 + tid * 16), 16, 0, 0); \
} while (0)

#define LDA4(base, mh) do {                                                    \
  a0 = *(const bf16x8*)(lds + (base) + offA[mh][0]);                           \
  a1 = *(const bf16x8*)(lds + (base) + offA[mh][1]);                           \
  a2 = *(const bf16x8*)(lds + (base) + offA[mh][2]);                           \
  a3 = *(const bf16x8*)(lds + (base) + offA[mh][3]);                           \
} while (0)

#define LDB4(base) do {                                                        \
  b0 = *(const bf16x8*)(lds + (base) + offB[0]);                               \
  b1 = *(const bf16x8*)(lds + (base) + offB[1]);                               \
  b2 = *(const bf16x8*)(lds + (base) + offB[2]);                               \
  b3 = *(const bf16x8*)(lds + (base) + offB[3]);                               \
} while (0)

#define MFMA16(mh) do {                                                        \
  acc[(mh)*4+0][0] = __builtin_amdgcn_mfma_f32_16x16x32_bf16(a0, b0, acc[(mh)*4+0][0], 0, 0, 0); \
  acc[(mh)*4+0][1] = __builtin_amdgcn_mfma_f32_16x16x32_bf16(a0, b1, acc[(mh)*4+0][1], 0, 0, 0); \
  acc[(mh)*4+0][2] = __builtin_amdgcn_mfma_f32_16x16x32_bf16(a0, b2, acc[(mh)*4+0][2], 0, 0, 0); \
  acc[(mh)*4+0][3] = __builtin_amdgcn_mfma_f32_16x16x32_bf16(a0, b3, acc[(mh)*4+0][3], 0, 0, 0); \
  acc[(mh)*4+1][0] = __builtin_amdgcn_mfma_f32_16x16x32_bf16(a1, b0, acc[(mh)*4+1][0], 0, 0, 0); \
  acc[(mh)*4+1][1] = __builtin_amdgcn_mfma_f32_16x16x32_bf16(a1, b1, acc[(mh)*4+1][1], 0, 0, 0); \
  acc[(mh)*4+1][2] = __builtin_amdgcn_mfma_f32_16x16x32_bf16(a1, b2, acc[(mh)*4+1][2], 0, 0, 0); \
  acc[(mh)*4+1][3] = __builtin_amdgcn_mfma_f32_16x16x32_bf16(a1, b3, acc[(mh)*4+1][3], 0, 0, 0); \
  acc[(mh)*4+2][0] = __builtin_amdgcn_mfma_f32_16x16x32_bf16(a2, b0, acc[(mh)*4+2][0], 0, 0, 0); \
  acc[(mh)*4+2][1] = __builtin_amdgcn_mfma_f32_16x16x32_bf16(a2, b1, acc[(mh)*4+2][1], 0, 0, 0); \
  acc[(mh)*4+2][2] = __builtin_amdgcn_mfma_f32_16x16x32_bf16(a2, b2, acc[(mh)*4+2][2], 0, 0, 0); \
  acc[(mh)*4+2][3] = __builtin_amdgcn_mfma_f32_16x16x32_bf16(a2, b3, acc[(mh)*4+2][3], 0, 0, 0); \
  acc[(mh)*4+3][0] = __builtin_amdgcn_mfma_f32_16x16x32_bf16(a3, b0, acc[(mh)*4+3][0], 0, 0, 0); \
  acc[(mh)*4+3][1] = __builtin_amdgcn_mfma_f32_16x16x32_bf16(a3, b1, acc[(mh)*4+3][1], 0, 0, 0); \
  acc[(mh)*4+3][2] = __builtin_amdgcn_mfma_f32_16x16x32_bf16(a3, b2, acc[(mh)*4+3][2], 0, 0, 0); \
  acc[(mh)*4+3][3] = __builtin_amdgcn_mfma_f32_16x16x32_bf16(a3, b3, acc[(mh)*4+3][3], 0, 0, 0); \
} while (0)

#define BAR()   __builtin_amdgcn_s_barrier()
#define LGKM0() do { asm volatile("s_waitcnt lgkmcnt(0)" ::: "memory");        \
                     __builtin_amdgcn_sched_barrier(0); } while (0)
#define VM(n)   asm volatile("s_waitcnt vmcnt(" #n ")" ::: "memory")
#define PRIO1() __builtin_amdgcn_s_setprio(1)
#define PRIO0() __builtin_amdgcn_s_setprio(0)

__global__ __launch_bounds__(512, 2) void gemm_bt_8ph(
    const bf16_t* __restrict__ A, const bf16_t* __restrict__ Bm,
    float* __restrict__ C) {
  __shared__ __align__(16) char lds[131072];

  const int tid  = threadIdx.x;
  const int lane = tid & 63;
  const int wave = tid >> 6;
  const int wm   = wave >> 2;  // 0..1  (M half of block)
  const int wn   = wave & 3;   // 0..3  (N quarter of block)

  // T1: XCD-aware swizzle; 256 blocks % 8 == 0 -> bijective
  const int sbid = (blockIdx.x & 7) * 32 + (blockIdx.x >> 3);
  const int bm   = sbid >> 4;
  const int bn   = sbid & 15;

  const int frow = lane & 15;
  const int c16  = (lane >> 4) * 16;  // 16B chunk within 64B row

  // ds_read byte offsets within a ks-half [256][32] region (T2-swizzled,
  // decorrelated: XOR with row bits 1-2, NOT bits 0-1)
  int offA[2][4], offB[4];
#pragma unroll
  for (int mh = 0; mh < 2; ++mh)
#pragma unroll
    for (int mi = 0; mi < 4; ++mi) {
      int r = wm * 128 + mh * 64 + mi * 16 + frow;
      offA[mh][mi] = r * 64 + (c16 ^ (((r >> 1) & 3) << 4));
    }
#pragma unroll
  for (int ni = 0; ni < 4; ++ni) {
    int r = wn * 64 + ni * 16 + frow;
    offB[ni] = r * 64 + (c16 ^ (((r >> 1) & 3) << 4));
  }

  // staging: write-side inverse of the read swizzle (rows srow and srow+128
  // have the same (row>>1)&3 only when... they differ; compute both)
  const int srow    = tid >> 2;
  const int schunk  = ((tid & 3) ^ ((srow >> 1) & 3)) * 8;
  const int schunk2 = ((tid & 3) ^ (((srow + 128) >> 1) & 3)) * 8;
  const bf16_t* Ag = A  + (size_t)bm * 256 * 4096;
  const bf16_t* Bg = Bm + (size_t)bn * 256 * 4096;

  f32x4 acc[8][4] = {};
  bf16x8 a0, a1, a2, a3, b0, b1, b2, b3;

  // ---- prologue: tile0 (full) + tile1 ks0; drain tile0, keep tile1 in flight
  STAGE(Ag, 0,  A0_B);
  STAGE(Bg, 0,  B0_B);
  STAGE(Ag, 32, A0_B + HALF);
  STAGE(Bg, 32, B0_B + HALF);
  STAGE(Ag, 64, A1_B);
  STAGE(Bg, 64, B1_B);
  VM(4);
  BAR();

  int kb = 0;
#pragma unroll 1
  for (int i = 0; i < 31; ++i, kb += 128) {
    // ph1: tile t ks0 mh0
    LDA4(A0_B, 0); LDB4(B0_B);
    STAGE(Ag, kb + 96, A1_B + HALF);
    BAR(); LGKM0(); PRIO1(); MFMA16(0); PRIO0(); BAR();
    // ph2: tile t ks0 mh1
    LDA4(A0_B, 1);
    STAGE(Bg, kb + 96, B1_B + HALF);
    BAR(); LGKM0(); PRIO1(); MFMA16(1); PRIO0(); BAR();
    // ph3: tile t ks1 mh0
    LDA4(A0_B + HALF, 0); LDB4(B0_B + HALF);
    STAGE(Ag, kb + 128, A0_B);
    BAR(); LGKM0(); PRIO1(); MFMA16(0); PRIO0(); BAR();
    // ph4: tile t ks1 mh1   [counted drain: tile t+1 fully landed]
    LDA4(A0_B + HALF, 1);
    STAGE(Bg, kb + 128, B0_B);
    BAR(); LGKM0(); PRIO1(); MFMA16(1); PRIO0(); VM(4); BAR();
    // ph5: tile t+1 ks0 mh0
    LDA4(A1_B, 0); LDB4(B1_B);
    STAGE(Ag, kb + 160, A0_B + HALF);
    BAR(); LGKM0(); PRIO1(); MFMA16(0); PRIO0(); BAR();
    // ph6: tile t+1 ks0 mh1
    LDA4(A1_B, 1);
    STAGE(Bg, kb + 160, B0_B + HALF);
    BAR(); LGKM0(); PRIO1(); MFMA16(1); PRIO0(); BAR();
    // ph7: tile t+1 ks1 mh0
    LDA4(A1_B + HALF, 0); LDB4(B1_B + HALF);
    STAGE(Ag, kb + 192, A1_B);
    BAR(); LGKM0(); PRIO1(); MFMA16(0); PRIO0(); BAR();
    // ph8: tile t+1 ks1 mh1  [counted drain: tile t+2 fully landed]
    LDA4(A1_B + HALF, 1);
    STAGE(Bg, kb + 192, B1_B);
    BAR(); LGKM0(); PRIO1(); MFMA16(1); PRIO0(); VM(4); BAR();
  }

  // ---- epilogue: tiles 62 (buf0) and 63 (buf1); kb == 3968
  LDA4(A0_B, 0); LDB4(B0_B);
  STAGE(Ag, kb + 96, A1_B + HALF);          // A(63)ks1
  BAR(); LGKM0(); PRIO1(); MFMA16(0); PRIO0(); BAR();
  LDA4(A0_B, 1);
  STAGE(Bg, kb + 96, B1_B + HALF);          // B(63)ks1
  BAR(); LGKM0(); PRIO1(); MFMA16(1); PRIO0(); BAR();
  LDA4(A0_B + HALF, 0); LDB4(B0_B + HALF);
  BAR(); LGKM0(); PRIO1(); MFMA16(0); PRIO0(); BAR();
  LDA4(A0_B + HALF, 1);
  BAR(); LGKM0(); PRIO1(); MFMA16(1); PRIO0(); VM(0); BAR();
  LDA4(A1_B, 0); LDB4(B1_B);
  BAR(); LGKM0(); PRIO1(); MFMA16(0); PRIO0(); BAR();
  LDA4(A1_B, 1);
  BAR(); LGKM0(); PRIO1(); MFMA16(1); PRIO0(); BAR();
  LDA4(A1_B + HALF, 0); LDB4(B1_B + HALF);
  BAR(); LGKM0(); PRIO1(); MFMA16(0); PRIO0(); BAR();
  LDA4(A1_B + HALF, 1);
  LGKM0(); PRIO1(); MFMA16(1); PRIO0();

  // ---- C write (D layout: col = lane&15, row = (lane>>4)*4 + jj)
#pragma unroll
  for (int mh = 0; mh < 2; ++mh)
#pragma unroll
    for (int mi = 0; mi < 4; ++mi)
#pragma unroll
      for (int ni = 0; ni < 4; ++ni) {
        const int row = bm * 256 + wm * 128 + mh * 64 + mi * 16 + (lane >> 4) * 4;
        const int col = bn * 256 + wn * 64 + ni * 16 + frow;
#pragma unroll
        for (int jj = 0; jj < 4; ++jj)
          C[(size_t)(row + jj) * 4096 + col] = acc[mh * 4 + mi][ni][jj];
      }
}

// ---------------------------------------------------------------------------
extern "C" void kernel_launch(void* const* d_in, const int* in_sizes, int n_in,
                              void* d_out, int out_size, void* d_ws, size_t ws_size,
                              hipStream_t stream) {
  const float* x     = (const float*)d_in[0];
  const float* wvals = (const float*)d_in[1];
  const int*   idx   = (const int*)d_in[2];   // (2, nnz): rows then cols
  const int*   mk    = (const int*)d_in[3];   // bool -> int32 on device (R1)
  const int    nnz   = in_sizes[1];

  // d_out doubles as the f32 W accumulator before GEMM overwrites it with y.
  float*  Wf32 = (float*)d_out;
  bf16_t* Wbf  = (bf16_t*)d_ws;
  bf16_t* xbf  = (bf16_t*)((char*)d_ws + (size_t)OUT_F * IN_F * sizeof(bf16_t));

  const size_t needed = (size_t)OUT_F * IN_F * 2 + (size_t)BATCH * IN_F * 2;
  if (ws_size < needed) return;

  hipMemsetAsync(d_out, 0, (size_t)OUT_F * IN_F * sizeof(float), stream);

  scatter_kernel<<<(nnz + 255) / 256, 256, 0, stream>>>(
      wvals, idx, idx + nnz, mk, Wf32, nnz);

  const int w8 = (OUT_F * IN_F) / 8;
  cvt_f32_bf16<<<(w8 + 255) / 256, 256, 0, stream>>>(
      (const float4*)Wf32, (uint4*)Wbf, w8);

  const int x8 = (BATCH * IN_F) / 8;
  cvt_f32_bf16<<<(x8 + 255) / 256, 256, 0, stream>>>(
      (const float4*)x, (uint4*)xbf, x8);

  gemm_bt_8ph<<<256, 512, 0, stream>>>(xbf, Wbf, (float*)d_out);
}

// Round 5
// 227.748 us; speedup vs baseline: 1.1632x; 1.0043x over previous
//
#include <hip/hip_runtime.h>
#include <cstdint>
#include <cstddef>

// Problem constants (SparseLinear: B=4096, IN=4096, OUT=4096, NNZ=1677722)
#define IN_F  4096
#define OUT_F 4096
#define BATCH 4096

typedef __bf16 bf16_t;
typedef __bf16 bf16x8 __attribute__((ext_vector_type(8)));
typedef float  f32x4  __attribute__((ext_vector_type(4)));

// ---------------------------------------------------------------------------
// f32 -> bf16 round-to-nearest-even (bit trick, deterministic)
// ---------------------------------------------------------------------------
__device__ __forceinline__ unsigned short f32_to_bf16_rne(float f) {
  union { float f; unsigned int u; } v;
  v.f = f;
  unsigned int u = v.u;
  return (unsigned short)((u + 0x7FFFu + ((u >> 16) & 1u)) >> 16);
}

__device__ __forceinline__ uint4 cvt8(float4 a, float4 b) {
  uint4 o;
  o.x = (unsigned)f32_to_bf16_rne(a.x) | ((unsigned)f32_to_bf16_rne(a.y) << 16);
  o.y = (unsigned)f32_to_bf16_rne(a.z) | ((unsigned)f32_to_bf16_rne(a.w) << 16);
  o.z = (unsigned)f32_to_bf16_rne(b.x) | ((unsigned)f32_to_bf16_rne(b.y) << 16);
  o.w = (unsigned)f32_to_bf16_rne(b.z) | ((unsigned)f32_to_bf16_rne(b.w) << 16);
  return o;
}

// ---------------------------------------------------------------------------
// Fused: zero the f32 W accumulator AND convert x -> bf16 (independent work,
// was 2 serialized passes). Grid-stride over 8-elem units.
// ---------------------------------------------------------------------------
#define WUNITS ((OUT_F * IN_F) / 8)   // 2097152
#define XUNITS ((BATCH * IN_F) / 8)   // 2097152

__global__ __launch_bounds__(256) void init_zero_cvtx(
    float4* __restrict__ Wf32v, const float4* __restrict__ xin,
    uint4* __restrict__ xbf) {
  const float4 z = {0.f, 0.f, 0.f, 0.f};
  for (int u = blockIdx.x * 256 + threadIdx.x; u < WUNITS + XUNITS;
       u += gridDim.x * 256) {
    if (u < WUNITS) {
      Wf32v[2 * u]     = z;
      Wf32v[2 * u + 1] = z;
    } else {
      const int i = u - WUNITS;
      xbf[i] = cvt8(xin[2 * i], xin[2 * i + 1]);
    }
  }
}

// ---------------------------------------------------------------------------
// Scatter-add COO weights into dense f32 W. mask is int32 on device (R1).
// ---------------------------------------------------------------------------
__global__ __launch_bounds__(256) void scatter_kernel(
    const float* __restrict__ w, const int* __restrict__ rows,
    const int* __restrict__ cols, const int* __restrict__ mask,
    float* __restrict__ W, int nnz) {
  int i = blockIdx.x * 256 + threadIdx.x;
  if (i < nnz) {
    if (mask[i] != 0) {
      atomicAdd(&W[(size_t)rows[i] * IN_F + cols[i]], w[i]);
    }
  }
}

// ---------------------------------------------------------------------------
// W f32 -> bf16 (after scatter)
// ---------------------------------------------------------------------------
__global__ __launch_bounds__(256) void cvt_f32_bf16(
    const float4* __restrict__ in, uint4* __restrict__ out, int n8) {
  int i = blockIdx.x * 256 + threadIdx.x;
  if (i >= n8) return;
  out[i] = cvt8(in[2 * i], in[2 * i + 1]);
}

// ---------------------------------------------------------------------------
// 256x256 8-phase bf16 GEMM, C = A @ Bm^T (both row-major [4096][4096]).
// T1 XCD swizzle + T2 LDS XOR-swizzle (R4: decorrelated, 0 conflicts) +
// T3/T4 8-phase counted vmcnt + T5 setprio.
// R5: deep uniform pipeline. One half-tile (2 gload_lds) staged per phase,
// VM(10) (= keep 5 halves) at the end of every even phase. Ledger:
//   stage slots (iter i, t=2i, kb=128i):
//     ph1:A(t+1)ks1   ph2:B(t+2)ks0  ph3:A(t+2)ks0  ph4:B(t+2)ks1
//     ph5:A(t+2)ks1   ph6:B(t+3)ks0  ph7:A(t+3)ks0  ph8:B(t+3)ks1
//   liveness (overwrite >=1 barrier after last read of old contents): A-halves
//   dead after the even phase that reads mh1; B-halves dead after the odd
//   phase that loads them (even phases reuse b0-b3 regs). All 8 slots are at
//   the earliest-safe phase. Every drain edge verified:
//     ph2-VM(10)-> (prev ph4/ph5) landed for ph3 reads
//     ph4-VM(10)-> (prev ph6/ph7) landed for ph5 reads
//     ph6-VM(10)-> (prev ph8 / ph1) landed for ph7 reads
//     ph8-VM(10)-> (ph2/ph3) landed for next-ph1 reads
//   Min slack: 5 phases (~1200cy) > 900cy HBM-miss latency. 14 loads in
//   flight peak, 10 after each drain; never drained to 0 in the loop.
// ---------------------------------------------------------------------------
#define A0_B 0
#define B0_B 32768
#define A1_B 65536
#define B1_B 98304
#define HALF 16384

#define STAGE(Xg, kpos, ldsbase) do {                                          \
  __builtin_amdgcn_global_load_lds(                                            \
    (const __attribute__((address_space(1))) void*)((Xg) + (size_t)srow * 4096 + (kpos) + schunk), \
    (__attribute__((address_space(3))) void*)(lds + (ldsbase) + tid * 16), 16, 0, 0); \
  __builtin_amdgcn_global_load_lds(                                            \
    (const __attribute__((address_space(1))) void*)((Xg) + (size_t)(srow + 128) * 4096 + (kpos) + schunk), \
    (__attribute__((address_space(3))) void*)(lds + (ldsbase) + 8192 + tid * 16), 16, 0, 0); \
} while (0)

#define LDA4(base, mh) do {                                                    \
  a0 = *(const bf16x8*)(lds + (base) + offA[mh][0]);                           \
  a1 = *(const bf16x8*)(lds + (base) + offA[mh][1]);                           \
  a2 = *(const bf16x8*)(lds + (base) + offA[mh][2]);                           \
  a3 = *(const bf16x8*)(lds + (base) + offA[mh][3]);                           \
} while (0)

#define LDB4(base) do {                                                        \
  b0 = *(const bf16x8*)(lds + (base) + offB[0]);                               \
  b1 = *(const bf16x8*)(lds + (base) + offB[1]);                               \
  b2 = *(const bf16x8*)(lds + (base) + offB[2]);                               \
  b3 = *(const bf16x8*)(lds + (base) + offB[3]);                               \
} while (0)

#define MFMA16(mh) do {                                                        \
  acc[(mh)*4+0][0] = __builtin_amdgcn_mfma_f32_16x16x32_bf16(a0, b0, acc[(mh)*4+0][0], 0, 0, 0); \
  acc[(mh)*4+0][1] = __builtin_amdgcn_mfma_f32_16x16x32_bf16(a0, b1, acc[(mh)*4+0][1], 0, 0, 0); \
  acc[(mh)*4+0][2] = __builtin_amdgcn_mfma_f32_16x16x32_bf16(a0, b2, acc[(mh)*4+0][2], 0, 0, 0); \
  acc[(mh)*4+0][3] = __builtin_amdgcn_mfma_f32_16x16x32_bf16(a0, b3, acc[(mh)*4+0][3], 0, 0, 0); \
  acc[(mh)*4+1][0] = __builtin_amdgcn_mfma_f32_16x16x32_bf16(a1, b0, acc[(mh)*4+1][0], 0, 0, 0); \
  acc[(mh)*4+1][1] = __builtin_amdgcn_mfma_f32_16x16x32_bf16(a1, b1, acc[(mh)*4+1][1], 0, 0, 0); \
  acc[(mh)*4+1][2] = __builtin_amdgcn_mfma_f32_16x16x32_bf16(a1, b2, acc[(mh)*4+1][2], 0, 0, 0); \
  acc[(mh)*4+1][3] = __builtin_amdgcn_mfma_f32_16x16x32_bf16(a1, b3, acc[(mh)*4+1][3], 0, 0, 0); \
  acc[(mh)*4+2][0] = __builtin_amdgcn_mfma_f32_16x16x32_bf16(a2, b0, acc[(mh)*4+2][0], 0, 0, 0); \
  acc[(mh)*4+2][1] = __builtin_amdgcn_mfma_f32_16x16x32_bf16(a2, b1, acc[(mh)*4+2][1], 0, 0, 0); \
  acc[(mh)*4+2][2] = __builtin_amdgcn_mfma_f32_16x16x32_bf16(a2, b2, acc[(mh)*4+2][2], 0, 0, 0); \
  acc[(mh)*4+2][3] = __builtin_amdgcn_mfma_f32_16x16x32_bf16(a2, b3, acc[(mh)*4+2][3], 0, 0, 0); \
  acc[(mh)*4+3][0] = __builtin_amdgcn_mfma_f32_16x16x32_bf16(a3, b0, acc[(mh)*4+3][0], 0, 0, 0); \
  acc[(mh)*4+3][1] = __builtin_amdgcn_mfma_f32_16x16x32_bf16(a3, b1, acc[(mh)*4+3][1], 0, 0, 0); \
  acc[(mh)*4+3][2] = __builtin_amdgcn_mfma_f32_16x16x32_bf16(a3, b2, acc[(mh)*4+3][2], 0, 0, 0); \
  acc[(mh)*4+3][3] = __builtin_amdgcn_mfma_f32_16x16x32_bf16(a3, b3, acc[(mh)*4+3][3], 0, 0, 0); \
} while (0)

#define BAR()   __builtin_amdgcn_s_barrier()
#define LGKM0() do { asm volatile("s_waitcnt lgkmcnt(0)" ::: "memory");        \
                     __builtin_amdgcn_sched_barrier(0); } while (0)
#define VM(n)   asm volatile("s_waitcnt vmcnt(" #n ")" ::: "memory")
#define PRIO1() __builtin_amdgcn_s_setprio(1)
#define PRIO0() __builtin_amdgcn_s_setprio(0)

__global__ __launch_bounds__(512, 2) void gemm_bt_8ph(
    const bf16_t* __restrict__ A, const bf16_t* __restrict__ Bm,
    float* __restrict__ C) {
  __shared__ __align__(16) char lds[131072];

  const int tid  = threadIdx.x;
  const int lane = tid & 63;
  const int wave = tid >> 6;
  const int wm   = wave >> 2;  // 0..1  (M half of block)
  const int wn   = wave & 3;   // 0..3  (N quarter of block)

  // T1: XCD-aware swizzle; 256 blocks % 8 == 0 -> bijective
  const int sbid = (blockIdx.x & 7) * 32 + (blockIdx.x >> 3);
  const int bm   = sbid >> 4;
  const int bn   = sbid & 15;

  const int frow = lane & 15;
  const int c16  = (lane >> 4) * 16;  // 16B chunk within 64B row

  // ds_read byte offsets within a ks-half [256][32] region (T2-swizzled,
  // decorrelated: XOR with row bits 1-2; R4-verified 0 conflicts)
  int offA[2][4], offB[4];
#pragma unroll
  for (int mh = 0; mh < 2; ++mh)
#pragma unroll
    for (int mi = 0; mi < 4; ++mi) {
      int r = wm * 128 + mh * 64 + mi * 16 + frow;
      offA[mh][mi] = r * 64 + (c16 ^ (((r >> 1) & 3) << 4));
    }
#pragma unroll
  for (int ni = 0; ni < 4; ++ni) {
    int r = wn * 64 + ni * 16 + frow;
    offB[ni] = r * 64 + (c16 ^ (((r >> 1) & 3) << 4));
  }

  // staging: write-side inverse of the read swizzle. Note (srow+128) has the
  // same ((row>>1)&3) as srow (bit7->bit6 stripped by &3), so one schunk.
  const int srow   = tid >> 2;
  const int schunk = ((tid & 3) ^ ((srow >> 1) & 3)) * 8;
  const bf16_t* Ag = A  + (size_t)bm * 256 * 4096;
  const bf16_t* Bg = Bm + (size_t)bn * 256 * 4096;

  f32x4 acc[8][4] = {};
  bf16x8 a0, a1, a2, a3, b0, b1, b2, b3;

  // ---- prologue: tile0 full + tile1 {Bks0, Aks0, Bks1} (steady-state issue
  // order); drain tile0's 8 loads, keep tile1's 6 in flight.
  STAGE(Ag, 0,  A0_B);
  STAGE(Bg, 0,  B0_B);
  STAGE(Ag, 32, A0_B + HALF);
  STAGE(Bg, 32, B0_B + HALF);
  STAGE(Bg, 64, B1_B);
  STAGE(Ag, 64, A1_B);
  STAGE(Bg, 96, B1_B + HALF);
  VM(6);
  BAR();

  int kb = 0;
#pragma unroll 1
  for (int i = 0; i < 31; ++i, kb += 128) {
    // ph1: tile t ks0 mh0
    LDA4(A0_B, 0); LDB4(B0_B);
    STAGE(Ag, kb + 96, A1_B + HALF);           // A(t+1)ks1
    BAR(); LGKM0(); PRIO1(); MFMA16(0); PRIO0(); BAR();
    // ph2: tile t ks0 mh1
    LDA4(A0_B, 1);
    STAGE(Bg, kb + 128, B0_B);                 // B(t+2)ks0
    BAR(); LGKM0(); PRIO1(); MFMA16(1); PRIO0(); VM(10); BAR();
    // ph3: tile t ks1 mh0
    LDA4(A0_B + HALF, 0); LDB4(B0_B + HALF);
    STAGE(Ag, kb + 128, A0_B);                 // A(t+2)ks0
    BAR(); LGKM0(); PRIO1(); MFMA16(0); PRIO0(); BAR();
    // ph4: tile t ks1 mh1
    LDA4(A0_B + HALF, 1);
    STAGE(Bg, kb + 160, B0_B + HALF);          // B(t+2)ks1
    BAR(); LGKM0(); PRIO1(); MFMA16(1); PRIO0(); VM(10); BAR();
    // ph5: tile t+1 ks0 mh0
    LDA4(A1_B, 0); LDB4(B1_B);
    STAGE(Ag, kb + 160, A0_B + HALF);          // A(t+2)ks1
    BAR(); LGKM0(); PRIO1(); MFMA16(0); PRIO0(); BAR();
    // ph6: tile t+1 ks0 mh1
    LDA4(A1_B, 1);
    STAGE(Bg, kb + 192, B1_B);                 // B(t+3)ks0
    BAR(); LGKM0(); PRIO1(); MFMA16(1); PRIO0(); VM(10); BAR();
    // ph7: tile t+1 ks1 mh0
    LDA4(A1_B + HALF, 0); LDB4(B1_B + HALF);
    STAGE(Ag, kb + 192, A1_B);                 // A(t+3)ks0
    BAR(); LGKM0(); PRIO1(); MFMA16(0); PRIO0(); BAR();
    // ph8: tile t+1 ks1 mh1
    LDA4(A1_B + HALF, 1);
    STAGE(Bg, kb + 224, B1_B + HALF);          // B(t+3)ks1
    BAR(); LGKM0(); PRIO1(); MFMA16(1); PRIO0(); VM(10); BAR();
  }

  // ---- epilogue: tiles 62 (buf0), 63 (buf1); kb == 3968. In flight on
  // entry: B62ks1, A62ks1, B63ks0, A63ks0, B63ks1 (10 loads).
  LDA4(A0_B, 0); LDB4(B0_B);
  STAGE(Ag, 4064, A1_B + HALF);                // A(63)ks1 (last stage)
  BAR(); LGKM0(); PRIO1(); MFMA16(0); PRIO0(); BAR();
  LDA4(A0_B, 1);
  BAR(); LGKM0(); PRIO1(); MFMA16(1); PRIO0(); VM(6); BAR();
  LDA4(A0_B + HALF, 0); LDB4(B0_B + HALF);
  BAR(); LGKM0(); PRIO1(); MFMA16(0); PRIO0(); BAR();
  LDA4(A0_B + HALF, 1);
  BAR(); LGKM0(); PRIO1(); MFMA16(1); PRIO0(); VM(2); BAR();
  LDA4(A1_B, 0); LDB4(B1_B);
  BAR(); LGKM0(); PRIO1(); MFMA16(0); PRIO0(); BAR();
  LDA4(A1_B, 1);
  BAR(); LGKM0(); PRIO1(); MFMA16(1); PRIO0(); VM(0); BAR();
  LDA4(A1_B + HALF, 0); LDB4(B1_B + HALF);
  BAR(); LGKM0(); PRIO1(); MFMA16(0); PRIO0(); BAR();
  LDA4(A1_B + HALF, 1);
  LGKM0(); PRIO1(); MFMA16(1); PRIO0();

  // ---- C write (D layout: col = lane&15, row = (lane>>4)*4 + jj)
#pragma unroll
  for (int mh = 0; mh < 2; ++mh)
#pragma unroll
    for (int mi = 0; mi < 4; ++mi)
#pragma unroll
      for (int ni = 0; ni < 4; ++ni) {
        const int row = bm * 256 + wm * 128 + mh * 64 + mi * 16 + (lane >> 4) * 4;
        const int col = bn * 256 + wn * 64 + ni * 16 + frow;
#pragma unroll
        for (int jj = 0; jj < 4; ++jj)
          C[(size_t)(row + jj) * 4096 + col] = acc[mh * 4 + mi][ni][jj];
      }
}

// ---------------------------------------------------------------------------
extern "C" void kernel_launch(void* const* d_in, const int* in_sizes, int n_in,
                              void* d_out, int out_size, void* d_ws, size_t ws_size,
                              hipStream_t stream) {
  const float* x     = (const float*)d_in[0];
  const float* wvals = (const float*)d_in[1];
  const int*   idx   = (const int*)d_in[2];   // (2, nnz): rows then cols
  const int*   mk    = (const int*)d_in[3];   // bool -> int32 on device (R1)
  const int    nnz   = in_sizes[1];

  // d_out doubles as the f32 W accumulator before GEMM overwrites it with y.
  float*  Wf32 = (float*)d_out;
  bf16_t* Wbf  = (bf16_t*)d_ws;
  bf16_t* xbf  = (bf16_t*)((char*)d_ws + (size_t)OUT_F * IN_F * sizeof(bf16_t));

  const size_t needed = (size_t)OUT_F * IN_F * 2 + (size_t)BATCH * IN_F * 2;
  if (ws_size < needed) return;

  // 1. fused: zero W accumulator + convert x -> bf16 (independent work)
  init_zero_cvtx<<<2048, 256, 0, stream>>>(
      (float4*)Wf32, (const float4*)x, (uint4*)xbf);

  // 2. scatter-add active weights (duplicates summed = coalesce semantics)
  scatter_kernel<<<(nnz + 255) / 256, 256, 0, stream>>>(
      wvals, idx, idx + nnz, mk, Wf32, nnz);

  // 3. W f32 -> bf16
  const int w8 = (OUT_F * IN_F) / 8;
  cvt_f32_bf16<<<(w8 + 255) / 256, 256, 0, stream>>>(
      (const float4*)Wf32, (uint4*)Wbf, w8);

  // 4. y = x @ W^T
  gemm_bt_8ph<<<256, 512, 0, stream>>>(xbf, Wbf, (float*)d_out);
}

// Round 6
// 212.257 us; speedup vs baseline: 1.2480x; 1.0730x over previous
//
#include <hip/hip_runtime.h>
#include <cstdint>
#include <cstddef>

// Problem constants (SparseLinear: B=4096, IN=4096, OUT=4096, NNZ=1677722)
#define IN_F  4096
#define OUT_F 4096
#define BATCH 4096

typedef __bf16 bf16_t;
typedef __bf16 bf16x8 __attribute__((ext_vector_type(8)));
typedef float  f32x4  __attribute__((ext_vector_type(4)));

// ---------------------------------------------------------------------------
// f32 -> bf16 round-to-nearest-even (bit trick, deterministic)
// ---------------------------------------------------------------------------
__device__ __forceinline__ unsigned short f32_to_bf16_rne(float f) {
  union { float f; unsigned int u; } v;
  v.f = f;
  unsigned int u = v.u;
  return (unsigned short)((u + 0x7FFFu + ((u >> 16) & 1u)) >> 16);
}

__device__ __forceinline__ uint4 cvt8(float4 a, float4 b) {
  uint4 o;
  o.x = (unsigned)f32_to_bf16_rne(a.x) | ((unsigned)f32_to_bf16_rne(a.y) << 16);
  o.y = (unsigned)f32_to_bf16_rne(a.z) | ((unsigned)f32_to_bf16_rne(a.w) << 16);
  o.z = (unsigned)f32_to_bf16_rne(b.x) | ((unsigned)f32_to_bf16_rne(b.y) << 16);
  o.w = (unsigned)f32_to_bf16_rne(b.z) | ((unsigned)f32_to_bf16_rne(b.w) << 16);
  return o;
}

// ---------------------------------------------------------------------------
// Fused: zero the bf16 W buffer AND convert x -> bf16. Grid-stride.
// ---------------------------------------------------------------------------
#define WU16 ((OUT_F * IN_F) / 8)     // 16B units of Wbf (2097152)
#define XUNITS ((BATCH * IN_F) / 8)   // 8-elem units of x (2097152)

__global__ __launch_bounds__(256) void init_zero_cvtx(
    uint4* __restrict__ Wbfv, const float4* __restrict__ xin,
    uint4* __restrict__ xbf) {
  const uint4 z = {0u, 0u, 0u, 0u};
  for (int u = blockIdx.x * 256 + threadIdx.x; u < WU16 + XUNITS;
       u += gridDim.x * 256) {
    if (u < WU16) {
      Wbfv[u] = z;
    } else {
      const int i = u - WU16;
      xbf[i] = cvt8(xin[2 * i], xin[2 * i + 1]);
    }
  }
}

// ---------------------------------------------------------------------------
// Scatter-add COO weights DIRECTLY into bf16 W via packed-bf16 atomic add
// (gfx950 global_atomic_pk_add_bf16). Eliminates the f32 accumulator, its
// 64MB zero-fill and the 96MB f32->bf16 conversion pass. Duplicates still
// sum (bf16 rounding per add; diff vs f32-sum ~8e-5, threshold 4.7e-2).
// mask is int32 on device (R1). Adding +0.0 to the partner half is identity.
// ---------------------------------------------------------------------------
__global__ __launch_bounds__(256) void scatter_bf16(
    const float* __restrict__ w, const int* __restrict__ rows,
    const int* __restrict__ cols, const int* __restrict__ mask,
    unsigned* __restrict__ Wpk, int nnz) {
  int i = blockIdx.x * 256 + threadIdx.x;
  if (i >= nnz) return;
  if (mask[i] == 0) return;
  const unsigned h = f32_to_bf16_rne(w[i]);
  const size_t e = (size_t)rows[i] * IN_F + cols[i];
  const unsigned data = (e & 1) ? (h << 16) : h;
  unsigned* p = Wpk + (e >> 1);
  asm volatile("global_atomic_pk_add_bf16 %0, %1, off"
               :: "v"(p), "v"(data) : "memory");
}

// ---------------------------------------------------------------------------
// 256x256 bf16 GEMM, C = A @ Bm^T (row-major [4096][4096]).
// R6: 4 phases/iter (32 MFMA each) — R5 showed vmem slack was NOT binding;
// the stall is the per-phase boundary (2 barriers + lgkm drain). Halving
// phase count halves boundary overhead per MFMA.
// T1 XCD swizzle + T2 decorrelated XOR swizzle (R4: 0 conflicts) + counted
// vmcnt + T5 setprio. LDS: 4 buffers x 2 ks-halves of [256 rows][32 bf16].
// Ledger (iter i, t=2i, kb=128i; STAGE pair = 4 gload_lds/phase):
//   P1 reads {A0h0,B0h0}=t.ks0,   stages t+1.ks1 -> {A1h1,B1h1} (died P4 i-1)
//   P2 reads {A0h1,B0h1}=t.ks1,   stages t+2.ks0 -> {A0h0,B0h0} (died P1)
//   P3 reads {A1h0,B1h0}=t+1.ks0, stages t+2.ks1 -> {A0h1,B0h1} (died P2)
//   P4 reads {A1h1,B1h1}=t+1.ks1, stages t+3.ks0 -> {A1h0,B1h0} (died P3)
//   VM(8) at every phase end: drains loads from 2 phases back; data staged
//   at P-3 is drained by end of P-1, read at P. 12 loads in flight peak.
// Epilogue (tiles 62,63): EP1 stages t63.ks1 then VM(8)/VM(4)/VM(0) drains.
// ---------------------------------------------------------------------------
#define A0_B 0
#define B0_B 32768
#define A1_B 65536
#define B1_B 98304
#define HALF 16384

#define STAGE(Xg, kpos, ldsbase) do {                                          \
  __builtin_amdgcn_global_load_lds(                                            \
    (const __attribute__((address_space(1))) void*)((Xg) + (size_t)srow * 4096 + (kpos) + schunk), \
    (__attribute__((address_space(3))) void*)(lds + (ldsbase) + tid * 16), 16, 0, 0); \
  __builtin_amdgcn_global_load_lds(                                            \
    (const __attribute__((address_space(1))) void*)((Xg) + (size_t)(srow + 128) * 4096 + (kpos) + schunk), \
    (__attribute__((address_space(3))) void*)(lds + (ldsbase) + 8192 + tid * 16), 16, 0, 0); \
} while (0)

#define LDALL(ab, bb) do {                                                     \
  a0 = *(const bf16x8*)(lds + (ab) + offA[0][0]);                              \
  a1 = *(const bf16x8*)(lds + (ab) + offA[0][1]);                              \
  a2 = *(const bf16x8*)(lds + (ab) + offA[0][2]);                              \
  a3 = *(const bf16x8*)(lds + (ab) + offA[0][3]);                              \
  a4 = *(const bf16x8*)(lds + (ab) + offA[1][0]);                              \
  a5 = *(const bf16x8*)(lds + (ab) + offA[1][1]);                              \
  a6 = *(const bf16x8*)(lds + (ab) + offA[1][2]);                              \
  a7 = *(const bf16x8*)(lds + (ab) + offA[1][3]);                              \
  b0 = *(const bf16x8*)(lds + (bb) + offB[0]);                                 \
  b1 = *(const bf16x8*)(lds + (bb) + offB[1]);                                 \
  b2 = *(const bf16x8*)(lds + (bb) + offB[2]);                                 \
  b3 = *(const bf16x8*)(lds + (bb) + offB[3]);                                 \
} while (0)

#define MQ(mh, A0_, A1_, A2_, A3_) do {                                        \
  acc[(mh)*4+0][0] = __builtin_amdgcn_mfma_f32_16x16x32_bf16(A0_, b0, acc[(mh)*4+0][0], 0, 0, 0); \
  acc[(mh)*4+0][1] = __builtin_amdgcn_mfma_f32_16x16x32_bf16(A0_, b1, acc[(mh)*4+0][1], 0, 0, 0); \
  acc[(mh)*4+0][2] = __builtin_amdgcn_mfma_f32_16x16x32_bf16(A0_, b2, acc[(mh)*4+0][2], 0, 0, 0); \
  acc[(mh)*4+0][3] = __builtin_amdgcn_mfma_f32_16x16x32_bf16(A0_, b3, acc[(mh)*4+0][3], 0, 0, 0); \
  acc[(mh)*4+1][0] = __builtin_amdgcn_mfma_f32_16x16x32_bf16(A1_, b0, acc[(mh)*4+1][0], 0, 0, 0); \
  acc[(mh)*4+1][1] = __builtin_amdgcn_mfma_f32_16x16x32_bf16(A1_, b1, acc[(mh)*4+1][1], 0, 0, 0); \
  acc[(mh)*4+1][2] = __builtin_amdgcn_mfma_f32_16x16x32_bf16(A1_, b2, acc[(mh)*4+1][2], 0, 0, 0); \
  acc[(mh)*4+1][3] = __builtin_amdgcn_mfma_f32_16x16x32_bf16(A1_, b3, acc[(mh)*4+1][3], 0, 0, 0); \
  acc[(mh)*4+2][0] = __builtin_amdgcn_mfma_f32_16x16x32_bf16(A2_, b0, acc[(mh)*4+2][0], 0, 0, 0); \
  acc[(mh)*4+2][1] = __builtin_amdgcn_mfma_f32_16x16x32_bf16(A2_, b1, acc[(mh)*4+2][1], 0, 0, 0); \
  acc[(mh)*4+2][2] = __builtin_amdgcn_mfma_f32_16x16x32_bf16(A2_, b2, acc[(mh)*4+2][2], 0, 0, 0); \
  acc[(mh)*4+2][3] = __builtin_amdgcn_mfma_f32_16x16x32_bf16(A2_, b3, acc[(mh)*4+2][3], 0, 0, 0); \
  acc[(mh)*4+3][0] = __builtin_amdgcn_mfma_f32_16x16x32_bf16(A3_, b0, acc[(mh)*4+3][0], 0, 0, 0); \
  acc[(mh)*4+3][1] = __builtin_amdgcn_mfma_f32_16x16x32_bf16(A3_, b1, acc[(mh)*4+3][1], 0, 0, 0); \
  acc[(mh)*4+3][2] = __builtin_amdgcn_mfma_f32_16x16x32_bf16(A3_, b2, acc[(mh)*4+3][2], 0, 0, 0); \
  acc[(mh)*4+3][3] = __builtin_amdgcn_mfma_f32_16x16x32_bf16(A3_, b3, acc[(mh)*4+3][3], 0, 0, 0); \
} while (0)

#define MFMA32() do { MQ(0, a0, a1, a2, a3); MQ(1, a4, a5, a6, a7); } while (0)

#define BAR()   __builtin_amdgcn_s_barrier()
#define LGKM0() do { asm volatile("s_waitcnt lgkmcnt(0)" ::: "memory");        \
                     __builtin_amdgcn_sched_barrier(0); } while (0)
#define VM(n)   asm volatile("s_waitcnt vmcnt(" #n ")" ::: "memory")
#define PRIO1() __builtin_amdgcn_s_setprio(1)
#define PRIO0() __builtin_amdgcn_s_setprio(0)

__global__ __launch_bounds__(512, 2) void gemm_bt_4ph(
    const bf16_t* __restrict__ A, const bf16_t* __restrict__ Bm,
    float* __restrict__ C) {
  __shared__ __align__(16) char lds[131072];

  const int tid  = threadIdx.x;
  const int lane = tid & 63;
  const int wave = tid >> 6;
  const int wm   = wave >> 2;  // 0..1  (M half of block)
  const int wn   = wave & 3;   // 0..3  (N quarter of block)

  // T1: XCD-aware swizzle; 256 blocks % 8 == 0 -> bijective
  const int sbid = (blockIdx.x & 7) * 32 + (blockIdx.x >> 3);
  const int bm   = sbid >> 4;
  const int bn   = sbid & 15;

  const int frow = lane & 15;
  const int c16  = (lane >> 4) * 16;  // 16B chunk within 64B row

  // ds_read byte offsets within a ks-half [256][32] region (T2-swizzled,
  // decorrelated: XOR with row bits 1-2; R4-verified 0 conflicts)
  int offA[2][4], offB[4];
#pragma unroll
  for (int mh = 0; mh < 2; ++mh)
#pragma unroll
    for (int mi = 0; mi < 4; ++mi) {
      int r = wm * 128 + mh * 64 + mi * 16 + frow;
      offA[mh][mi] = r * 64 + (c16 ^ (((r >> 1) & 3) << 4));
    }
#pragma unroll
  for (int ni = 0; ni < 4; ++ni) {
    int r = wn * 64 + ni * 16 + frow;
    offB[ni] = r * 64 + (c16 ^ (((r >> 1) & 3) << 4));
  }

  // staging: write-side inverse of the read swizzle ((srow+128) keeps the
  // same ((row>>1)&3): bit7 is stripped by &3)
  const int srow   = tid >> 2;
  const int schunk = ((tid & 3) ^ ((srow >> 1) & 3)) * 8;
  const bf16_t* Ag = A  + (size_t)bm * 256 * 4096;
  const bf16_t* Bg = Bm + (size_t)bn * 256 * 4096;

  f32x4 acc[8][4] = {};
  bf16x8 a0, a1, a2, a3, a4, a5, a6, a7, b0, b1, b2, b3;

  // ---- prologue: tile0 full + tile1 ks0 (12 loads); drain tile0's 8.
  STAGE(Ag, 0,  A0_B);
  STAGE(Bg, 0,  B0_B);
  STAGE(Ag, 32, A0_B + HALF);
  STAGE(Bg, 32, B0_B + HALF);
  STAGE(Ag, 64, A1_B);
  STAGE(Bg, 64, B1_B);
  VM(8);
  BAR();

  int kb = 0;
#pragma unroll 1
  for (int i = 0; i < 31; ++i, kb += 128) {
    // P1: tile t ks0 | stage t+1 ks1
    LDALL(A0_B, B0_B);
    STAGE(Ag, kb + 96, A1_B + HALF);
    STAGE(Bg, kb + 96, B1_B + HALF);
    BAR(); LGKM0(); PRIO1(); MFMA32(); PRIO0(); VM(8); BAR();
    // P2: tile t ks1 | stage t+2 ks0
    LDALL(A0_B + HALF, B0_B + HALF);
    STAGE(Ag, kb + 128, A0_B);
    STAGE(Bg, kb + 128, B0_B);
    BAR(); LGKM0(); PRIO1(); MFMA32(); PRIO0(); VM(8); BAR();
    // P3: tile t+1 ks0 | stage t+2 ks1
    LDALL(A1_B, B1_B);
    STAGE(Ag, kb + 160, A0_B + HALF);
    STAGE(Bg, kb + 160, B0_B + HALF);
    BAR(); LGKM0(); PRIO1(); MFMA32(); PRIO0(); VM(8); BAR();
    // P4: tile t+1 ks1 | stage t+3 ks0
    LDALL(A1_B + HALF, B1_B + HALF);
    STAGE(Ag, kb + 192, A1_B);
    STAGE(Bg, kb + 192, B1_B);
    BAR(); LGKM0(); PRIO1(); MFMA32(); PRIO0(); VM(8); BAR();
  }

  // ---- epilogue: tiles 62 (buf0), 63 (buf1); kb == 3968.
  // In flight on entry: t62.ks1 (4), t63.ks0 (4).
  LDALL(A0_B, B0_B);                       // t62 ks0
  STAGE(Ag, 4064, A1_B + HALF);            // t63 ks1 (last stage)
  STAGE(Bg, 4064, B1_B + HALF);
  BAR(); LGKM0(); PRIO1(); MFMA32(); PRIO0(); VM(8); BAR();
  LDALL(A0_B + HALF, B0_B + HALF);         // t62 ks1
  BAR(); LGKM0(); PRIO1(); MFMA32(); PRIO0(); VM(4); BAR();
  LDALL(A1_B, B1_B);                       // t63 ks0
  BAR(); LGKM0(); PRIO1(); MFMA32(); PRIO0(); VM(0); BAR();
  LDALL(A1_B + HALF, B1_B + HALF);         // t63 ks1
  LGKM0(); PRIO1(); MFMA32(); PRIO0();

  // ---- C write (D layout: col = lane&15, row = (lane>>4)*4 + jj)
#pragma unroll
  for (int mh = 0; mh < 2; ++mh)
#pragma unroll
    for (int mi = 0; mi < 4; ++mi)
#pragma unroll
      for (int ni = 0; ni < 4; ++ni) {
        const int row = bm * 256 + wm * 128 + mh * 64 + mi * 16 + (lane >> 4) * 4;
        const int col = bn * 256 + wn * 64 + ni * 16 + frow;
#pragma unroll
        for (int jj = 0; jj < 4; ++jj)
          C[(size_t)(row + jj) * 4096 + col] = acc[mh * 4 + mi][ni][jj];
      }
}

// ---------------------------------------------------------------------------
extern "C" void kernel_launch(void* const* d_in, const int* in_sizes, int n_in,
                              void* d_out, int out_size, void* d_ws, size_t ws_size,
                              hipStream_t stream) {
  const float* x     = (const float*)d_in[0];
  const float* wvals = (const float*)d_in[1];
  const int*   idx   = (const int*)d_in[2];   // (2, nnz): rows then cols
  const int*   mk    = (const int*)d_in[3];   // bool -> int32 on device (R1)
  const int    nnz   = in_sizes[1];

  // ws: [0,32MB) = W bf16, [32MB,64MB) = x bf16. No f32 accumulator anymore.
  bf16_t* Wbf = (bf16_t*)d_ws;
  bf16_t* xbf = (bf16_t*)((char*)d_ws + (size_t)OUT_F * IN_F * sizeof(bf16_t));

  const size_t needed = (size_t)OUT_F * IN_F * 2 + (size_t)BATCH * IN_F * 2;
  if (ws_size < needed) return;

  // 1. fused: zero bf16 W + convert x -> bf16
  init_zero_cvtx<<<2048, 256, 0, stream>>>(
      (uint4*)Wbf, (const float4*)x, (uint4*)xbf);

  // 2. scatter-add active weights directly in bf16 (packed atomic)
  scatter_bf16<<<(nnz + 255) / 256, 256, 0, stream>>>(
      wvals, idx, idx + nnz, mk, (unsigned*)Wbf, nnz);

  // 3. y = x @ W^T
  gemm_bt_4ph<<<256, 512, 0, stream>>>(xbf, Wbf, (float*)d_out);
}